// Round 7
// baseline (224.798 us; speedup 1.0000x reference)
//
#include <hip/hip_runtime.h>

#define N_NODES 100000
#define N_EDGES 6400000
#define IN_DIM 10
#define HIDDEN 16

#define NBLK 512                            // grid: all blocks co-resident (2/CU by LDS)
#define NSTRM 511                           // streams of SNODES nodes; sid = dst/196
#define SNODES 196                          // 511*196 >= 100000; nid fits 8 bits
#define RBIN 38                             // LDS slots per (block,stream): λ=24.5, P(>38)~0.5%
#define EPB 12500                           // edges per block: 512*12500 = 6.4M exact
#define CAPB 18432                          // region slots per stream (mean ~16.5k, 17σ margin)
#define CAPO 128                            // overflow slots per stream
#define XELEMS (N_NODES * IN_DIM)
#define XE_PER_BLK 1954                     // ceil(1M/512)
#define SENT 0xFFFFFFFFu                    // pad sentinel; valid packs < 0x02000000
#define FPS 262144.0f                       // fixed-point scale 2^18
#define FPSI (1.0f / 262144.0f)

typedef unsigned uv4 __attribute__((ext_vector_type(4)));
typedef int iv4 __attribute__((ext_vector_type(4)));
typedef float fv4 __attribute__((ext_vector_type(4)));

__device__ __forceinline__ float bf_lo(unsigned u) { return __uint_as_float(u << 16); }
__device__ __forceinline__ float bf_hi(unsigned u) { return __uint_as_float(u & 0xffff0000u); }
__device__ __forceinline__ int f2i(float f) { return __float2int_rn(f * FPS); }

// ---------------- Fused kernel: bin -> grid barrier -> accumulate -> epilogue ----------------
// Round-7: (a) bin at STREAM granularity (511 bins) so the drain stays the simple fast
// pad-16 full-line burst (R6's drain-time partition cost +28us: serial 2-pass scan with
// 8-way bank conflicts) yet pass 2 still gets PURE streams (R6's validated pass-2 gain);
// (b) fuse both passes into ONE kernel with a device-scope arrive-and-spin grid barrier:
// the persistent ~70us gap between sum(kernel durs) and dur_us (3 dispatches + the
// pass1->pass2 drain bubble) is the largest remaining cost. All 512 blocks co-resident:
// LDS 79.7KB -> exactly 2 blocks/CU (159.7 <= 163.8KB), 1024 threads/CU <= 2048.
// Barrier release/acquire at agent scope emits the cross-XCD L2 writeback/invalidate, so
// phase-2 blocks see phase-1 region/xp writes from other XCDs.
__global__ __launch_bounds__(512, 4) void sage_fused(const int* __restrict__ src,
                                                     const int* __restrict__ dst,
                                                     const float* __restrict__ x,
                                                     int* __restrict__ gcur,
                                                     int* __restrict__ gover,
                                                     int* __restrict__ bar,
                                                     unsigned* __restrict__ region,
                                                     unsigned* __restrict__ over,
                                                     unsigned short* __restrict__ xp,
                                                     const float* __restrict__ W_l,
                                                     const float* __restrict__ b_l,
                                                     const float* __restrict__ W_r,
                                                     float* __restrict__ out) {
    __shared__ union {
        struct { int lcur[NSTRM]; unsigned lbin[NSTRM * RBIN]; } p1;   // 79,716 B
        struct { int acci[SNODES][IN_DIM + 1];                         // stride 11 bank-coprime
                 float sWl[IN_DIM * HIDDEN], sWr[IN_DIM * HIDDEN], sb[HIDDEN]; } p2;
    } sm;
    int t = threadIdx.x, bid = blockIdx.x;

    for (int b = t; b < NSTRM; b += 512) sm.p1.lcur[b] = 0;

    // xpack slice: x fp32 (40B rows) -> bf16 rows at 32B stride (1 line per gather)
    int xbase = bid * XE_PER_BLK;
    int xend = min(xbase + XE_PER_BLK, XELEMS);
    for (int e = xbase + t; e < xend; e += 512) {
        int row = e / 10, k = e - row * 10;
        unsigned bits = __float_as_uint(__builtin_nontemporal_load(&x[e]));
        xp[(size_t)row * 16 + k] = (unsigned short)((bits + 0x8000u) >> 16);
    }
    __syncthreads();

    // binning: uint4 edge loads, 1 LDS atomic + 1 LDS store per edge; bin = stream id
    int base = bid * EPB;
    int end = base + EPB;
#define BIN1(ss, dd)                                                                     \
    {                                                                                    \
        int s = (ss), d = (dd);                                                          \
        if ((unsigned)s < N_NODES && (unsigned)d < N_NODES) {                            \
            unsigned sd = (unsigned)d / (unsigned)SNODES;                                \
            unsigned nid = (unsigned)d - sd * (unsigned)SNODES;                          \
            unsigned pack = (unsigned)s | (nid << 17);                                   \
            int pos = atomicAdd(&sm.p1.lcur[sd], 1);                                     \
            if (pos < RBIN) {                                                            \
                sm.p1.lbin[sd * RBIN + pos] = pack;                                      \
            } else {                                                                     \
                int gg = atomicAdd(&gover[sd], 1);                                       \
                if (gg < CAPO) over[(size_t)sd * CAPO + gg] = pack;                      \
            }                                                                            \
        }                                                                                \
    }
    for (int i = base + (t << 2); i < end; i += 2048) {
        iv4 sv = __builtin_nontemporal_load((const iv4*)(src + i));
        iv4 dv = __builtin_nontemporal_load((const iv4*)(dst + i));
        BIN1(sv.x, dv.x); BIN1(sv.y, dv.y); BIN1(sv.z, dv.z); BIN1(sv.w, dv.w);
    }
    __syncthreads();

    // drain: simple R5-style pad-16 -> every run is a 64B-aligned full-line burst;
    // one bin per thread, <=12 uint4 stores. Cap-spill routes to the over-list.
    for (int b = t; b < NSTRM; b += 512) {
        int f = min(sm.p1.lcur[b], RBIN);
        if (f > 0) {
            int fp = (f + 15) & ~15;                 // 16, 32 or 48
            int g = atomicAdd(&gcur[b], fp);         // stays 16-aligned
            if (g + fp <= CAPB) {
                unsigned* dp = region + (size_t)b * CAPB;
                for (int j = 0; j < fp; j += 4) {
                    uint4 v;
                    v.x = (j + 0 < f) ? sm.p1.lbin[b * RBIN + j + 0] : SENT;
                    v.y = (j + 1 < f) ? sm.p1.lbin[b * RBIN + j + 1] : SENT;
                    v.z = (j + 2 < f) ? sm.p1.lbin[b * RBIN + j + 2] : SENT;
                    v.w = (j + 3 < f) ? sm.p1.lbin[b * RBIN + j + 3] : SENT;
                    *(uint4*)&dp[g + j] = v;
                }
            } else {
                for (int j = 0; j < f; ++j) {
                    int gg = atomicAdd(&gover[b], 1);
                    if (gg < CAPO) over[(size_t)b * CAPO + gg] = sm.p1.lbin[b * RBIN + j];
                }
            }
        }
    }

    // ---- device-scope grid barrier (all NBLK blocks co-resident by construction) ----
    __syncthreads();
    if (t == 0) {
        __hip_atomic_fetch_add(bar, 1, __ATOMIC_RELEASE, __HIP_MEMORY_SCOPE_AGENT);
        while (__hip_atomic_load(bar, __ATOMIC_RELAXED, __HIP_MEMORY_SCOPE_AGENT) < NBLK) {}
        (void)__hip_atomic_load(bar, __ATOMIC_ACQUIRE, __HIP_MEMORY_SCOPE_AGENT);
    }
    __syncthreads();

    if (bid >= NSTRM) return;                    // block 511 has no stream

    // ---- phase 2: walk own PURE stream; fixed-point int32 LDS accumulate ----
    int (*acci)[IN_DIM + 1] = sm.p2.acci;
    for (int i = t; i < SNODES * (IN_DIM + 1); i += 512) ((int*)acci)[i] = 0;
    if (t < IN_DIM * HIDDEN) { sm.p2.sWl[t] = W_l[t]; sm.p2.sWr[t] = W_r[t]; }
    if (t < HIDDEN) sm.p2.sb[t] = b_l[t];
    __syncthreads();

#define GATH(r, p, qq)                                                                   \
    {                                                                                    \
        unsigned sid = ((r) == SENT) ? 0u : ((r) & 0x1FFFFu);  /* pads hit hot line */   \
        const unsigned* pp = (const unsigned*)(xp + (size_t)sid * 16);                   \
        p = *(const uint4*)pp;                                                           \
        qq = pp[4];                                                                      \
    }
#define ACCUM(r, p, qq)                                                                  \
    if ((r) != SENT) {                                                                   \
        int nd = ((r) >> 17) & 0xFF;                                                     \
        int* a = acci[nd];                                                               \
        atomicAdd(a + 0, f2i(bf_lo(p.x))); atomicAdd(a + 1, f2i(bf_hi(p.x)));            \
        atomicAdd(a + 2, f2i(bf_lo(p.y))); atomicAdd(a + 3, f2i(bf_hi(p.y)));            \
        atomicAdd(a + 4, f2i(bf_lo(p.z))); atomicAdd(a + 5, f2i(bf_hi(p.z)));            \
        atomicAdd(a + 6, f2i(bf_lo(p.w))); atomicAdd(a + 7, f2i(bf_hi(p.w)));            \
        atomicAdd(a + 8, f2i(bf_lo(qq)));  atomicAdd(a + 9, f2i(bf_hi(qq)));             \
        atomicAdd(a + 10, 1);                                                            \
    }

    int n = min(gcur[bid], CAPB);                // multiple of 16 -> clean uint4 walk
    int n4 = n >> 2;
    const uv4* reg4 = (const uv4*)(region + (size_t)bid * CAPB);
    {
        uv4 rv;
        if (t < n4) rv = __builtin_nontemporal_load(&reg4[t]);
        for (int i = t; i < n4; i += 512) {
            uv4 nx;
            int inx = i + 512;
            if (inx < n4) nx = __builtin_nontemporal_load(&reg4[inx]);
            uint4 p0, p1, p2, p3; unsigned q0, q1, q2, q3;
            GATH(rv.x, p0, q0); GATH(rv.y, p1, q1); GATH(rv.z, p2, q2); GATH(rv.w, p3, q3);
            ACCUM(rv.x, p0, q0); ACCUM(rv.y, p1, q1); ACCUM(rv.z, p2, q2); ACCUM(rv.w, p3, q3);
            rv = nx;
        }
    }
    int m = min(gover[bid], CAPO);               // pure overflow list: no filter
    const unsigned* ov = over + (size_t)bid * CAPO;
    for (int i = t; i < m; i += 512) {
        unsigned r = __builtin_nontemporal_load(&ov[i]);
        uint4 p; unsigned qq;
        GATH(r, p, qq);
        ACCUM(r, p, qq);
    }
    __syncthreads();

    // fused epilogue: mean + GEMV + bias; exact fp32 root term. 2 threads/node, 8 h each.
    {
        int nl = t >> 1;                         // 0..255 (valid < SNODES)
        int hb = (t & 1) << 3;                   // 0 or 8
        if (nl < SNODES) {
            int node = bid * SNODES + nl;
            if (node < N_NODES) {
                float cnt = (float)acci[nl][IN_DIM];
                float inv = FPSI / fmaxf(cnt, 1.0f);
                const float* xr = x + (size_t)node * IN_DIM;
                float o[8];
#pragma unroll
                for (int h = 0; h < 8; ++h) o[h] = sm.p2.sb[hb + h];
#pragma unroll
                for (int k = 0; k < IN_DIM; ++k) {
                    float m2 = (float)acci[nl][k] * inv;
                    float xk = xr[k];
                    const float* wl = &sm.p2.sWl[k * HIDDEN + hb];
                    const float* wr = &sm.p2.sWr[k * HIDDEN + hb];
#pragma unroll
                    for (int h = 0; h < 8; ++h) o[h] += m2 * wl[h] + xk * wr[h];
                }
                fv4 oa = {o[0], o[1], o[2], o[3]};
                fv4 ob = {o[4], o[5], o[6], o[7]};
                float* op = out + (size_t)node * HIDDEN + hb;
                __builtin_nontemporal_store(oa, (fv4*)op);
                __builtin_nontemporal_store(ob, (fv4*)(op + 4));
            }
        }
    }
}

// ---------------- fallback (round-1 style, correct, slow) for tiny ws ----------------
__global__ void sage_scatter_fb(const float* __restrict__ x, const int* __restrict__ src,
                                const int* __restrict__ dst, float* __restrict__ summed,
                                float* __restrict__ counts) {
    int e = blockIdx.x * blockDim.x + threadIdx.x;
    if (e >= N_EDGES) return;
    int s = src[e], d = dst[e];
    if ((unsigned)s >= N_NODES || (unsigned)d >= N_NODES) return;
    const float* xs = x + (size_t)s * IN_DIM;
    float* sm = summed + (size_t)d * IN_DIM;
#pragma unroll
    for (int k = 0; k < IN_DIM; ++k) atomicAdd(&sm[k], xs[k]);
    atomicAdd(&counts[d], 1.0f);
}

__global__ void sage_out_fb(const float* __restrict__ x, const float* __restrict__ summed,
                            const float* __restrict__ counts, const float* __restrict__ W_l,
                            const float* __restrict__ b_l, const float* __restrict__ W_r,
                            float* __restrict__ out) {
    __shared__ float sWl[IN_DIM * HIDDEN], sWr[IN_DIM * HIDDEN], sb[HIDDEN];
    int t = threadIdx.x;
    if (t < IN_DIM * HIDDEN) { sWl[t] = W_l[t]; sWr[t] = W_r[t]; }
    if (t < HIDDEN) sb[t] = b_l[t];
    __syncthreads();
    int tid = blockIdx.x * blockDim.x + t;
    if (tid >= N_NODES * HIDDEN) return;
    int node = tid >> 4, h = tid & (HIDDEN - 1);
    float inv = 1.0f / fmaxf(counts[node], 1.0f);
    const float* sm = summed + (size_t)node * IN_DIM;
    const float* xr = x + (size_t)node * IN_DIM;
    float acc = sb[h];
#pragma unroll
    for (int k = 0; k < IN_DIM; ++k)
        acc += sm[k] * inv * sWl[k * HIDDEN + h] + xr[k] * sWr[k * HIDDEN + h];
    out[tid] = acc;
}

extern "C" void kernel_launch(void* const* d_in, const int* in_sizes, int n_in,
                              void* d_out, int out_size, void* d_ws, size_t ws_size,
                              hipStream_t stream) {
    const float* x   = (const float*)d_in[0];
    const int*   ei  = (const int*)d_in[1];   // [2, E] flat: first E = src, next E = dst
    const float* W_l = (const float*)d_in[2];
    const float* b_l = (const float*)d_in[3];
    const float* W_r = (const float*)d_in[4];
    float* out = (float*)d_out;
    const int* src = ei;
    const int* dst = ei + N_EDGES;

    const size_t region_off = 8192;                               // gcur@0, gover@4096, bar@8000
    const size_t region_sz  = (size_t)NSTRM * CAPB * 4;           // 37.68 MB
    const size_t xp_off     = region_off + region_sz;             // 32B-aligned
    const size_t xp_sz      = (size_t)N_NODES * 16 * 2;           // 3.2 MB
    const size_t over_off   = xp_off + xp_sz;
    const size_t over_sz    = (size_t)NSTRM * CAPO * 4;           // 0.26 MB
    const size_t need = over_off + over_sz;                       // ~41.1 MB

    if (ws_size >= need) {
        int* gcur = (int*)d_ws;
        int* gover = (int*)((char*)d_ws + 4096);
        int* bar = (int*)((char*)d_ws + 8000);
        unsigned* region = (unsigned*)((char*)d_ws + region_off);
        unsigned short* xp = (unsigned short*)((char*)d_ws + xp_off);
        unsigned* over = (unsigned*)((char*)d_ws + over_off);

        // zero cursors + barrier counter (ws re-poisoned each call)
        hipMemsetAsync(d_ws, 0, 8192, stream);

        sage_fused<<<NBLK, 512, 0, stream>>>(src, dst, x, gcur, gover, bar,
                                             region, over, xp, W_l, b_l, W_r, out);
    } else {
        float* summed = (float*)d_ws;
        float* counts = summed + (size_t)N_NODES * IN_DIM;
        hipMemsetAsync(d_ws, 0, (size_t)(N_NODES * IN_DIM + N_NODES) * sizeof(float), stream);
        int threads = 256;
        int eblocks = (N_EDGES + threads - 1) / threads;
        sage_scatter_fb<<<eblocks, threads, 0, stream>>>(x, src, dst, summed, counts);
        int oblocks = (N_NODES * HIDDEN + threads - 1) / threads;
        sage_out_fb<<<oblocks, threads, 0, stream>>>(x, summed, counts, W_l, b_l, W_r, out);
    }
}

// Round 9
// 179.962 us; speedup vs baseline: 1.2491x; 1.2491x over previous
//
#include <hip/hip_runtime.h>

#define N_NODES 100000
#define N_EDGES 6400000
#define IN_DIM 10
#define HIDDEN 16

#define SID_SHIFT 7
#define SNODES 128                          // nodes per stream; stream = final consumer
#define NSTRM 782                           // ceil(100000/128) pure streams
#define RBIN 20                             // LDS slots per (block,bin): λ=13.1, P(>20)~2%
#define EPB 10240                           // edges per pass-1 block (20/thread)
#define NB1 ((N_EDGES + EPB - 1) / EPB)     // 625 blocks (exact)
#define CAPB 12544                          // region slots per stream (mean ~11.7k, +6σ), 16-aligned
#define CAPO 192                            // overflow slots per stream (expect ~24)
#define XELEMS (N_NODES * IN_DIM)
#define XE_PER_BLK ((XELEMS + NB1 - 1) / NB1)  // 1600
#define SENT 0xFFFFFFFFu                    // pad sentinel; valid packs < 0x01000000
#define FPS 262144.0f                       // fixed-point scale 2^18
#define FPSI (1.0f / 262144.0f)

typedef unsigned uv4 __attribute__((ext_vector_type(4)));
typedef int iv4 __attribute__((ext_vector_type(4)));
typedef float fv4 __attribute__((ext_vector_type(4)));

__device__ __forceinline__ float bf_lo(unsigned u) { return __uint_as_float(u << 16); }
__device__ __forceinline__ float bf_hi(unsigned u) { return __uint_as_float(u & 0xffff0000u); }
__device__ __forceinline__ int f2i(float f) { return __float2int_rn(f * FPS); }

// ---------------- Pass 1: xpack + bin at STREAM granularity; simple pad-16 drain ----------------
// Round-9 = Round-8 resubmitted verbatim (R8 bench died to a container-level infra error;
// kernel audit found no hang/crash vector: no spin loops, ws 43.05MB < proven 43.3MB,
// all caps spill-guarded). Rationale unchanged:
// R7 proved binning at the final consumer's granularity keeps the drain trivially
// full-line (pad-16, 64B-exclusive -> no cross-XCD RMW, R5 lesson); R6 proved pure
// streams are what pass 2 wants. 782 bins (sid = d>>7), λ=13.1, RBIN=20.
// LDS 64.2KB -> 2 blocks/CU. NO drain-time partitioning (R6's +28µs mistake).
__global__ __launch_bounds__(512, 4) void bin_edges_xpack(const int* __restrict__ src,
                                                          const int* __restrict__ dst,
                                                          const float* __restrict__ x,
                                                          int* __restrict__ gcur,
                                                          int* __restrict__ gover,
                                                          unsigned* __restrict__ region,
                                                          unsigned* __restrict__ over,
                                                          unsigned short* __restrict__ xp) {
    __shared__ int lcur[NSTRM];              // 3.1 KB
    __shared__ unsigned lbin[NSTRM * RBIN];  // 61.1 KB; total 64.2 KB -> 2 blocks/CU
    int t = threadIdx.x;
    for (int b = t; b < NSTRM; b += 512) lcur[b] = 0;

    // xpack slice: x fp32 (40B rows) -> bf16 rows at 32B stride (1 line per gather)
    int xbase = blockIdx.x * XE_PER_BLK;
    int xend = min(xbase + XE_PER_BLK, XELEMS);
    for (int e = xbase + t; e < xend; e += 512) {
        int row = e / 10, k = e - row * 10;
        unsigned bits = __float_as_uint(__builtin_nontemporal_load(&x[e]));
        xp[(size_t)row * 16 + k] = (unsigned short)((bits + 0x8000u) >> 16);
    }
    __syncthreads();

    // binning: uint4 edge loads, 1 LDS atomic + 1 LDS store per edge; bin = stream id
    int base = blockIdx.x * EPB;
    int end = min(base + EPB, N_EDGES);
#define BIN1(ss, dd)                                                                     \
    {                                                                                    \
        int s = (ss), d = (dd);                                                          \
        if ((unsigned)s < N_NODES && (unsigned)d < N_NODES) {                            \
            unsigned sd = (unsigned)d >> SID_SHIFT;                                      \
            unsigned pack = (unsigned)s | (((unsigned)d & (SNODES - 1)) << 17);          \
            int pos = atomicAdd(&lcur[sd], 1);                                           \
            if (pos < RBIN) {                                                            \
                lbin[sd * RBIN + pos] = pack;                                            \
            } else {                                                                     \
                int gg = atomicAdd(&gover[sd], 1);                                       \
                if (gg < CAPO) over[(size_t)sd * CAPO + gg] = pack;                      \
            }                                                                            \
        }                                                                                \
    }
    for (int i = base + (t << 2); i < end; i += 2048) {
        iv4 sv = __builtin_nontemporal_load((const iv4*)(src + i));
        iv4 dv = __builtin_nontemporal_load((const iv4*)(dst + i));
        BIN1(sv.x, dv.x); BIN1(sv.y, dv.y); BIN1(sv.z, dv.z); BIN1(sv.w, dv.w);
    }
    __syncthreads();

    // drain: pad-16 -> every run is a 64B-aligned full-line burst (amp 1.0, block-
    // exclusive lines); pad slots carry SENT, rejected free in pass 2. Cap-spill
    // routes to the over-list (never dropped).
    for (int b = t; b < NSTRM; b += 512) {
        int f = min(lcur[b], RBIN);
        if (f > 0) {
            int fp = (f + 15) & ~15;                 // 16 or 32
            int g = atomicAdd(&gcur[b], fp);         // stays 16-aligned
            if (g + fp <= CAPB) {
                unsigned* dp = region + (size_t)b * CAPB;
                for (int j = 0; j < fp; j += 4) {
                    uint4 v;
                    v.x = (j + 0 < f) ? lbin[b * RBIN + j + 0] : SENT;
                    v.y = (j + 1 < f) ? lbin[b * RBIN + j + 1] : SENT;
                    v.z = (j + 2 < f) ? lbin[b * RBIN + j + 2] : SENT;
                    v.w = (j + 3 < f) ? lbin[b * RBIN + j + 3] : SENT;
                    *(uint4*)&dp[g + j] = v;
                }
            } else {
                for (int j = 0; j < f; ++j) {
                    int gg = atomicAdd(&gover[b], 1);
                    if (gg < CAPO) over[(size_t)b * CAPO + gg] = lbin[b * RBIN + j];
                }
            }
        }
    }
}

// ---------------- Pass 2: one block per PURE stream; LDS INT-atomic accumulate ----------------
// 782 blocks x 512 threads; acci[128][11] = 5.5KB -> 4 blocks/CU (thread-limited), ~24
// waves/CU resident (the TLP that R7's fusion destroyed). Every non-SENT record belongs
// to this block: no filter, full lane occupancy on ds_add. Prefetched region walk keeps
// the next uint4 in flight under the gather+ds body. Fixed-point int32 accumulate
// (scale 2^18): native fire-and-forget ds_add_u32 (fp32 LDS atomics are CAS loops).
#define GATH(r, p, qq)                                                                   \
    {                                                                                    \
        unsigned sid = ((r) == SENT) ? 0u : ((r) & 0x1FFFFu);  /* pads hit hot line */   \
        const unsigned* pp = (const unsigned*)(xp + (size_t)sid * 16);                   \
        p = *(const uint4*)pp;                                                           \
        qq = pp[4];                                                                      \
    }
#define ACCUM(r, p, qq)                                                                  \
    if ((r) != SENT) {                                                                   \
        int nd = ((r) >> 17) & (SNODES - 1);                                             \
        int* a = acci[nd];                                                               \
        atomicAdd(a + 0, f2i(bf_lo(p.x))); atomicAdd(a + 1, f2i(bf_hi(p.x)));            \
        atomicAdd(a + 2, f2i(bf_lo(p.y))); atomicAdd(a + 3, f2i(bf_hi(p.y)));            \
        atomicAdd(a + 4, f2i(bf_lo(p.z))); atomicAdd(a + 5, f2i(bf_hi(p.z)));            \
        atomicAdd(a + 6, f2i(bf_lo(p.w))); atomicAdd(a + 7, f2i(bf_hi(p.w)));            \
        atomicAdd(a + 8, f2i(bf_lo(qq)));  atomicAdd(a + 9, f2i(bf_hi(qq)));             \
        atomicAdd(a + 10, 1);                                                            \
    }

__global__ __launch_bounds__(512, 8) void bucket_accum_out(const unsigned short* __restrict__ xp,
                                                           const float* __restrict__ x,
                                                           const int* __restrict__ gcur,
                                                           const int* __restrict__ gover,
                                                           const unsigned* __restrict__ region,
                                                           const unsigned* __restrict__ over,
                                                           const float* __restrict__ W_l,
                                                           const float* __restrict__ b_l,
                                                           const float* __restrict__ W_r,
                                                           float* __restrict__ out) {
    __shared__ int acci[SNODES][IN_DIM + 1];        // 5.5 KB, stride 11 bank-coprime
    __shared__ float sWl[IN_DIM * HIDDEN], sWr[IN_DIM * HIDDEN], sb[HIDDEN];

    int b = blockIdx.x;                          // stream id, 0..781
    int t = threadIdx.x;
    for (int i = t; i < SNODES * (IN_DIM + 1); i += 512) ((int*)acci)[i] = 0;
    if (t < IN_DIM * HIDDEN) { sWl[t] = W_l[t]; sWr[t] = W_r[t]; }
    if (t < HIDDEN) sb[t] = b_l[t];
    __syncthreads();

    int n = min(gcur[b], CAPB);                  // multiple of 16 -> clean uint4 walk
    int n4 = n >> 2;
    const uv4* reg4 = (const uv4*)(region + (size_t)b * CAPB);

    // prefetched single walk over the pure stream
    {
        uv4 rv;
        if (t < n4) rv = __builtin_nontemporal_load(&reg4[t]);
        for (int i = t; i < n4; i += 512) {
            uv4 nx;
            int inx = i + 512;
            if (inx < n4) nx = __builtin_nontemporal_load(&reg4[inx]);
            uint4 p0, p1, p2, p3; unsigned q0, q1, q2, q3;
            GATH(rv.x, p0, q0); GATH(rv.y, p1, q1); GATH(rv.z, p2, q2); GATH(rv.w, p3, q3);
            ACCUM(rv.x, p0, q0); ACCUM(rv.y, p1, q1); ACCUM(rv.z, p2, q2); ACCUM(rv.w, p3, q3);
            rv = nx;
        }
    }
    // overflow list: pure per-stream, no filter
    int m = min(gover[b], CAPO);
    const unsigned* ov = over + (size_t)b * CAPO;
    for (int i = t; i < m; i += 512) {
        unsigned r = __builtin_nontemporal_load(&ov[i]);
        uint4 p; unsigned qq;
        GATH(r, p, qq);
        ACCUM(r, p, qq);
    }
    __syncthreads();

    // fused epilogue: mean + GEMV + bias; exact fp32 root term. 4 threads/node, 4 h each.
    {
        int nl = t >> 2;                         // 0..127
        int hq = (t & 3) << 2;                   // 0,4,8,12
        int node = b * SNODES + nl;
        if (node < N_NODES) {
            float cnt = (float)acci[nl][IN_DIM];
            float inv = FPSI / fmaxf(cnt, 1.0f); // fixed-point unscale fused into mean
            const float* xr = x + (size_t)node * IN_DIM;
            float o0 = sb[hq], o1 = sb[hq + 1], o2 = sb[hq + 2], o3 = sb[hq + 3];
#pragma unroll
            for (int k = 0; k < IN_DIM; ++k) {
                float m2 = (float)acci[nl][k] * inv;  // LDS broadcast across the 4 lanes
                float xk = xr[k];                // same line for 4 lanes -> 1 req
                const float* wl = &sWl[k * HIDDEN + hq];
                const float* wr = &sWr[k * HIDDEN + hq];
                o0 += m2 * wl[0] + xk * wr[0];
                o1 += m2 * wl[1] + xk * wr[1];
                o2 += m2 * wl[2] + xk * wr[2];
                o3 += m2 * wl[3] + xk * wr[3];
            }
            fv4 o = {o0, o1, o2, o3};
            __builtin_nontemporal_store(o, (fv4*)(out + (size_t)node * HIDDEN + hq));
        }
    }
}

// ---------------- fallback (round-1 style, correct, slow) for tiny ws ----------------
__global__ void sage_scatter_fb(const float* __restrict__ x, const int* __restrict__ src,
                                const int* __restrict__ dst, float* __restrict__ summed,
                                float* __restrict__ counts) {
    int e = blockIdx.x * blockDim.x + threadIdx.x;
    if (e >= N_EDGES) return;
    int s = src[e], d = dst[e];
    if ((unsigned)s >= N_NODES || (unsigned)d >= N_NODES) return;
    const float* xs = x + (size_t)s * IN_DIM;
    float* sm = summed + (size_t)d * IN_DIM;
#pragma unroll
    for (int k = 0; k < IN_DIM; ++k) atomicAdd(&sm[k], xs[k]);
    atomicAdd(&counts[d], 1.0f);
}

__global__ void sage_out_fb(const float* __restrict__ x, const float* __restrict__ summed,
                            const float* __restrict__ counts, const float* __restrict__ W_l,
                            const float* __restrict__ b_l, const float* __restrict__ W_r,
                            float* __restrict__ out) {
    __shared__ float sWl[IN_DIM * HIDDEN], sWr[IN_DIM * HIDDEN], sb[HIDDEN];
    int t = threadIdx.x;
    if (t < IN_DIM * HIDDEN) { sWl[t] = W_l[t]; sWr[t] = W_r[t]; }
    if (t < HIDDEN) sb[t] = b_l[t];
    __syncthreads();
    int tid = blockIdx.x * blockDim.x + t;
    if (tid >= N_NODES * HIDDEN) return;
    int node = tid >> 4, h = tid & (HIDDEN - 1);
    float inv = 1.0f / fmaxf(counts[node], 1.0f);
    const float* sm = summed + (size_t)node * IN_DIM;
    const float* xr = x + (size_t)node * IN_DIM;
    float acc = sb[h];
#pragma unroll
    for (int k = 0; k < IN_DIM; ++k)
        acc += sm[k] * inv * sWl[k * HIDDEN + h] + xr[k] * sWr[k * HIDDEN + h];
    out[tid] = acc;
}

extern "C" void kernel_launch(void* const* d_in, const int* in_sizes, int n_in,
                              void* d_out, int out_size, void* d_ws, size_t ws_size,
                              hipStream_t stream) {
    const float* x   = (const float*)d_in[0];
    const int*   ei  = (const int*)d_in[1];   // [2, E] flat: first E = src, next E = dst
    const float* W_l = (const float*)d_in[2];
    const float* b_l = (const float*)d_in[3];
    const float* W_r = (const float*)d_in[4];
    float* out = (float*)d_out;
    const int* src = ei;
    const int* dst = ei + N_EDGES;

    const size_t region_off = 8192;                               // gcur[782]@0, gover[782]@4096
    const size_t region_sz  = (size_t)NSTRM * CAPB * 4;           // 39.24 MB
    const size_t xp_off     = region_off + region_sz;             // 32B-aligned (CAPB 16-aligned)
    const size_t xp_sz      = (size_t)N_NODES * 16 * 2;           // 3.2 MB
    const size_t over_off   = xp_off + xp_sz;
    const size_t over_sz    = (size_t)NSTRM * CAPO * 4;           // 0.6 MB
    const size_t need = over_off + over_sz;                       // ~43.0 MB

    if (ws_size >= need) {
        int* gcur = (int*)d_ws;
        int* gover = (int*)((char*)d_ws + 4096);
        unsigned* region = (unsigned*)((char*)d_ws + region_off);
        unsigned short* xp = (unsigned short*)((char*)d_ws + xp_off);
        unsigned* over = (unsigned*)((char*)d_ws + over_off);

        // zero both cursor arrays (ws re-poisoned each call)
        hipMemsetAsync(d_ws, 0, 8192, stream);

        bin_edges_xpack<<<NB1, 512, 0, stream>>>(src, dst, x, gcur, gover, region, over, xp);
        bucket_accum_out<<<NSTRM, 512, 0, stream>>>(xp, x, gcur, gover, region, over,
                                                    W_l, b_l, W_r, out);
    } else {
        float* summed = (float*)d_ws;
        float* counts = summed + (size_t)N_NODES * IN_DIM;
        hipMemsetAsync(d_ws, 0, (size_t)(N_NODES * IN_DIM + N_NODES) * sizeof(float), stream);
        int threads = 256;
        int eblocks = (N_EDGES + threads - 1) / threads;
        sage_scatter_fb<<<eblocks, threads, 0, stream>>>(x, src, dst, summed, counts);
        int oblocks = (N_NODES * HIDDEN + threads - 1) / threads;
        sage_out_fb<<<oblocks, threads, 0, stream>>>(x, summed, counts, W_l, b_l, W_r, out);
    }
}